// Round 4
// baseline (209.923 us; speedup 1.0000x reference)
//
#include <hip/hip_runtime.h>

// out[b,o] = x[b,:] @ W_lin[:,o] + x[b] @ W_nl[o] @ x[b]
// Symmetric GEMM form: K=640 via 10 folded 8x8 block-pairs of W_nl+W_nl^T.
// BARRIER-FREE design: each wave owns a 16-row tile AND one 16-col half,
// and runs ALL 20 k-steps itself -> no K-split, no LDS, no reduce, no
// __syncthreads anywhere. B' fragments: 20 x bf16x8 = 80 VGPRs (W_nl is
// L2-resident; loaded once per wave). x rows live per-lane in registers
// (8 x floatx4); the 4 lanes of a row issue identical global addresses
// (HW merges). Per-quad scalars x[4k+q] come from 3 v_cndmask selects.
// Linear part: full-scale W_lin, one MFMA (wave owns its col-half).
// Grid 768 = exactly 3 blocks/CU at 3 waves/SIMD (reg cap 170).

typedef __attribute__((ext_vector_type(8))) __bf16 bf16x8;
typedef __attribute__((ext_vector_type(4))) float floatx4;

#define NB    524288
#define NWT   (NB / 16 * 2)   // 65536 wave-tiles = 32768 row-tiles x 2 col-halves
#define NWAV  3072            // 768 blocks x 4 waves
#define ST    NWAV

__global__ __launch_bounds__(256, 3)
void nnode_kernel(const float* __restrict__ x, const float* __restrict__ Wlin,
                  const float* __restrict__ Wnl, float* __restrict__ out) {
    const int tid  = threadIdx.x;
    const int lane = tid & 63;
    const int q    = lane >> 4;   // quad: A k-window / C row group
    const int col  = lane & 15;   // output column (within half) / A row
    const int gw   = blockIdx.x * 4 + (tid >> 6);   // global wave id 0..3071
    const int ch   = gw & 1;      // col half (ST even -> fixed per wave)
    const int ocol = ch * 16 + col;

    // pair table: step t -> pair p=t>>1, half h=t&1
    constexpr int PA[10] = {0,0,0,0,1,1,1,2,2,3};
    constexpr int PB[10] = {0,1,2,3,1,2,3,2,3,3};

    // ---- B' fragments for ALL 20 k-steps, this col half only ----
    // B'[k=q*8+j][ocol] = W'[a,b][u=4h+q][v=j][ocol], W' = fold(W_nl+W_nl^T)
    bf16x8 bW[20];
    {
        const float* wb = Wnl + (size_t)ocol * 1024;
        #pragma unroll
        for (int t = 0; t < 20; ++t) {
            const int a = PA[t >> 1], b = PB[t >> 1];
            const int u = 4 * (t & 1) + q;
            floatx4 v0 = *(const floatx4*)(wb + (8 * a + u) * 32 + 8 * b);
            floatx4 v1 = *(const floatx4*)(wb + (8 * a + u) * 32 + 8 * b + 4);
            if (a != b) {   // off-diagonal pair: += W_nl[o, 8b+v, 8a+u]
                #pragma unroll
                for (int j = 0; j < 4; ++j) {
                    v0[j] += wb[(8 * b + j) * 32 + 8 * a + u];
                    v1[j] += wb[(8 * b + 4 + j) * 32 + 8 * a + u];
                }
            }
            bf16x8 f;
            #pragma unroll
            for (int j = 0; j < 4; ++j) { f[j] = (__bf16)v0[j]; f[j + 4] = (__bf16)v1[j]; }
            bW[t] = f;
        }
    }
    // linear B fragment (full scale: this wave owns its col-half exclusively)
    bf16x8 bl;
    #pragma unroll
    for (int j = 0; j < 8; ++j)
        bl[j] = (__bf16)Wlin[(q * 8 + j) * 32 + ocol];

    const bool q1 = (q & 1) != 0;
    const bool q2 = (q & 2) != 0;

    // tiles for this wave: wt = gw + k*ST, k < n  (1024 waves do 22, rest 21)
    const int n = (gw < (NWT - 21 * NWAV)) ? 22 : 21;

    floatx4 X[8];   // this lane's x row (row = rt*16 + col), 32 floats
    int wt = gw;
    for (int k = 0; k < n; ++k, wt += ST) {
        const size_t rbase = ((size_t)(wt >> 1) * 16 + col) * 32;
        #pragma unroll
        for (int i = 0; i < 8; ++i)
            X[i] = *(const floatx4*)(x + rbase + i * 4);

        // per-quad scalars: S[k2] = x_row[4*k2 + q]  (3 cndmask each)
        float S[8];
        #pragma unroll
        for (int k2 = 0; k2 < 8; ++k2) {
            float lo = q1 ? X[k2][1] : X[k2][0];
            float hi = q1 ? X[k2][3] : X[k2][2];
            S[k2] = q2 ? hi : lo;
        }

        floatx4 acc = {0.f, 0.f, 0.f, 0.f};

        // linear: A elements q*8+j  -> windows X[2q], X[2q+1] via selects
        {
            floatx4 lo0 = q1 ? X[2] : X[0], hi0 = q1 ? X[6] : X[4];
            floatx4 la0 = q2 ? hi0 : lo0;
            floatx4 lo1 = q1 ? X[3] : X[1], hi1 = q1 ? X[7] : X[5];
            floatx4 la1 = q2 ? hi1 : lo1;
            bf16x8 af;
            #pragma unroll
            for (int j = 0; j < 4; ++j) { af[j] = (__bf16)la0[j]; af[j + 4] = (__bf16)la1[j]; }
            acc = __builtin_amdgcn_mfma_f32_16x16x32_bf16(af, bl, acc, 0, 0, 0);
        }

        // 20 symmetric-packed k-steps: af[j] = x[8a+4h+q] * x[8b+j]
        #pragma unroll
        for (int t = 0; t < 20; ++t) {
            const int a = PA[t >> 1], b = PB[t >> 1];
            const float sc = S[2 * a + (t & 1)];
            floatx4 p0 = sc * X[2 * b];
            floatx4 p1 = sc * X[2 * b + 1];
            bf16x8 af;
            #pragma unroll
            for (int j = 0; j < 4; ++j) { af[j] = (__bf16)p0[j]; af[j + 4] = (__bf16)p1[j]; }
            acc = __builtin_amdgcn_mfma_f32_16x16x32_bf16(af, bW[t], acc, 0, 0, 0);
        }

        // C/D: col = lane&15 -> ocol, row = q*4 + r for acc[r]
        float* op = out + ((size_t)(wt >> 1) * 16 + q * 4) * 32 + ocol;
        op[0]  = acc[0];
        op[32] = acc[1];
        op[64] = acc[2];
        op[96] = acc[3];
    }
}

extern "C" void kernel_launch(void* const* d_in, const int* in_sizes, int n_in,
                              void* d_out, int out_size, void* d_ws, size_t ws_size,
                              hipStream_t stream) {
    const float* x    = (const float*)d_in[0];
    const float* Wlin = (const float*)d_in[1];
    const float* Wnl  = (const float*)d_in[2];
    float* out        = (float*)d_out;
    nnode_kernel<<<dim3(768), dim3(256), 0, stream>>>(x, Wlin, Wnl, out);
}

// Round 6
// 162.743 us; speedup vs baseline: 1.2899x; 1.2899x over previous
//
#include <hip/hip_runtime.h>

// out[b,o] = x[b,:] @ W_lin[:,o] + x[b] @ W_nl[o] @ x[b]
// Symmetric GEMM form (K=640 via 10 folded 8x8 block-pairs of W_nl+W_nl^T),
// 20 k-steps split across 4 waves (5 each), B' fragments in registers
// (R2-verified). NEW this round: each lane loads its WHOLE 32-float x row
// as 8x ds_read_b128 from the XW xor-swizzled LDS tile (R3-verified layout;
// quad-broadcast + 2-way banked), and all window/scalar accesses become
// REGISTER selects (R4-verified ternary math) with compile-time step
// constants per wave (wave-uniform 4-way branch). This removes the 12x b128
// + 5x b32 per-lane window reads and their latency chains. Staging, prefetch,
// quarter-scaled linear, padded scalar reduce: R2 verbatim (all verified).

typedef __attribute__((ext_vector_type(8))) __bf16 bf16x8;
typedef __attribute__((ext_vector_type(4))) float floatx4;
typedef __attribute__((ext_vector_type(2))) float floatx2;

#define NB     524288
#define NTILES (NB / 16)       // 32768
#define GRID   1024            // 4 blocks/CU, 32 iters/block, no tail
#define ITERS  (NTILES / GRID)
#define REDW   544             // 16 rows * 34 floats (pad 32->34)
#define REDB   (4 * REDW)

// xor-swizzled x word (R3-verified): row r (0..15), element e (0..31)
__device__ __forceinline__ int XW(int r, int e) {
    return r * 32 + ((((e >> 2) ^ (r & 7)) << 2) | (e & 3));
}

__device__ __forceinline__ bf16x8 pack8(floatx4 a, floatx4 b) {
    bf16x8 f;
    #pragma unroll
    for (int j = 0; j < 4; ++j) { f[j] = (__bf16)a[j]; f[j + 4] = (__bf16)b[j]; }
    return f;
}

__global__ __launch_bounds__(256, 4)
void nnode_kernel(const float* __restrict__ x, const float* __restrict__ Wlin,
                  const float* __restrict__ Wnl, float* __restrict__ out) {
    __shared__ __align__(16) float xs[2][512];    // 4 KiB, swizzled 16x32
    __shared__ __align__(16) float red[2][REDB];  // 17 KiB

    const int tid  = threadIdx.x;
    const int wave = tid >> 6;
    const int lane = tid & 63;
    const int q    = lane >> 4;   // quad: A k-window / C row group
    const int col  = lane & 15;   // output column / A row

    // ---- B' fragments: wave w owns global steps t = 5w..5w+4 (R2 loop) ----
    bf16x8 bW[5][2];
    #pragma unroll
    for (int kl = 0; kl < 5; ++kl) {
        const int t  = wave * 5 + kl;
        const int p  = t >> 1, h = t & 1;
        const int pa = (p < 4) ? 0 : ((p < 7) ? 1 : ((p < 9) ? 2 : 3));
        const int pb = p - ((p < 4) ? 0 : ((p < 7) ? 3 : ((p < 9) ? 5 : 6)));
        const int i1 = 8 * pa + 4 * h + q;        // = 8a + u
        #pragma unroll
        for (int tt = 0; tt < 2; ++tt) {
            const float* base = Wnl + (size_t)(col + 16 * tt) * 1024;
            floatx4 v0 = *(const floatx4*)(base + i1 * 32 + 8 * pb);
            floatx4 v1 = *(const floatx4*)(base + i1 * 32 + 8 * pb + 4);
            if (pa != pb) {   // fold transposed block: += W_nl[o, 8b+v, 8a+u]
                #pragma unroll
                for (int j = 0; j < 4; ++j) {
                    v0[j] += base[(size_t)(8 * pb + j) * 32 + i1];
                    v1[j] += base[(size_t)(8 * pb + 4 + j) * 32 + i1];
                }
            }
            bW[kl][tt] = pack8(v0, v1);
        }
    }

    // ---- linear-part B fragments, quarter-scaled (R2 verbatim) ----
    bf16x8 bl0, bl1;
    #pragma unroll
    for (int j = 0; j < 8; ++j) {
        bl0[j] = (__bf16)(0.25f * Wlin[(q * 8 + j) * 32 + col]);
        bl1[j] = (__bf16)(0.25f * Wlin[(q * 8 + j) * 32 + col + 16]);
    }

    const bool q1 = (q & 1) != 0;
    const bool q2 = (q & 2) != 0;

    const int srow  = tid >> 4;          // staging/reduce row 0..15
    const int scol2 = (tid & 15) * 2;    // staging/reduce elem pair

    // ---- prologue: stage tile blockIdx.x into xs[0] (R2 map, XW word) ----
    {
        floatx2 v = *(const floatx2*)(x + (size_t)blockIdx.x * 512 + tid * 2);
        *(floatx2*)&xs[0][XW(srow, scol2)] = v;
    }
    __syncthreads();

    int it = 0;
    for (int tile = blockIdx.x; tile < NTILES; tile += GRID, ++it) {
        const int b0  = tile << 4;
        const int cur = it & 1;

        // prefetch next tile (coalesced 2KB/block); landed after compute
        floatx2 pre;
        if (it < ITERS - 1)
            pre = *(const floatx2*)(x + ((size_t)b0 + GRID * 16) * 32 + tid * 2);

        // full row -> registers: 8x b128 (quad broadcast + 2-way banked)
        const float* xb = xs[cur];
        floatx4 X[8];
        #pragma unroll
        for (int j = 0; j < 8; ++j)
            X[j] = *(const floatx4*)&xb[XW(col, 4 * j)];

        floatx4 acc0 = {0.f, 0.f, 0.f, 0.f};
        floatx4 acc1 = {0.f, 0.f, 0.f, 0.f};

        // scalar select X[i][q] via 3 cndmask (R4-verified)
        #define SELQ(V) (q2 ? (q1 ? (V)[3] : (V)[2]) : (q1 ? (V)[1] : (V)[0]))

        // linear part (quarter-scaled; window at q*8 via register selects)
        {
            floatx4 la0 = q2 ? (q1 ? X[6] : X[4]) : (q1 ? X[2] : X[0]);
            floatx4 la1 = q2 ? (q1 ? X[7] : X[5]) : (q1 ? X[3] : X[1]);
            bf16x8 af = pack8(la0, la1);
            acc0 = __builtin_amdgcn_mfma_f32_16x16x32_bf16(af, bl0, acc0, 0, 0, 0);
            acc1 = __builtin_amdgcn_mfma_f32_16x16x32_bf16(af, bl1, acc1, 0, 0, 0);
        }

        // one symmetric-packed k-step: af[j] = x[8a+4h+q] * x[8b+j]
        #define STEP(A, B, H, KL) {                                             \
            const float sc = SELQ(X[2 * (A) + (H)]);                            \
            floatx4 p0 = sc * X[2 * (B)];                                       \
            floatx4 p1 = sc * X[2 * (B) + 1];                                   \
            bf16x8 af = pack8(p0, p1);                                          \
            acc0 = __builtin_amdgcn_mfma_f32_16x16x32_bf16(af, bW[KL][0], acc0, 0, 0, 0); \
            acc1 = __builtin_amdgcn_mfma_f32_16x16x32_bf16(af, bW[KL][1], acc1, 0, 0, 0); }

        // wave-uniform branch; (a,b,h) literals match t = 5*wave + kl
        if (wave == 0) {
            STEP(0,0,0,0) STEP(0,0,1,1) STEP(0,1,0,2) STEP(0,1,1,3) STEP(0,2,0,4)
        } else if (wave == 1) {
            STEP(0,2,1,0) STEP(0,3,0,1) STEP(0,3,1,2) STEP(1,1,0,3) STEP(1,1,1,4)
        } else if (wave == 2) {
            STEP(1,2,0,0) STEP(1,2,1,1) STEP(1,3,0,2) STEP(1,3,1,3) STEP(2,2,0,4)
        } else {
            STEP(2,2,1,0) STEP(2,3,0,1) STEP(2,3,1,2) STEP(3,3,0,3) STEP(3,3,1,4)
        }
        #undef STEP
        #undef SELQ

        // ---- partials to LDS (R2 verbatim: row = q*4+r, col = col(+16)) ----
        float* rp = red[cur] + wave * REDW;
        #pragma unroll
        for (int r = 0; r < 4; ++r) {
            rp[(q * 4 + r) * 34 + col]      = acc0[r];
            rp[(q * 4 + r) * 34 + col + 16] = acc1[r];
        }
        // land the prefetched tile into the other x buffer
        if (it < ITERS - 1)
            *(floatx2*)&xs[cur ^ 1][XW(srow, scol2)] = pre;
        __syncthreads();

        // ---- reduce 4 partials; thread owns elems [2*tid, 2*tid+1] ----
        const float* rb = red[cur];
        floatx2 sum = *(const floatx2*)(rb + srow * 34 + scol2);
        #pragma unroll
        for (int w = 1; w < 4; ++w) {
            floatx2 pp = *(const floatx2*)(rb + w * REDW + srow * 34 + scol2);
            sum.x += pp.x; sum.y += pp.y;
        }
        *(floatx2*)(out + (size_t)b0 * 32 + tid * 2) = sum;
        // double-buffered xs/red; the single barrier orders reuse
    }
}

extern "C" void kernel_launch(void* const* d_in, const int* in_sizes, int n_in,
                              void* d_out, int out_size, void* d_ws, size_t ws_size,
                              hipStream_t stream) {
    const float* x    = (const float*)d_in[0];
    const float* Wlin = (const float*)d_in[1];
    const float* Wnl  = (const float*)d_in[2];
    float* out        = (float*)d_out;
    nnode_kernel<<<dim3(GRID), dim3(256), 0, stream>>>(x, Wlin, Wnl, out);
}